// Round 15
// baseline (1453.896 us; speedup 1.0000x reference)
//
#include <hip/hip_runtime.h>

// PtrNet greedy decode, B=16, N=1000, H=128, M=2, 16 steps.
// R13 champion (XCD-affinity, 944us) + FUSED GLIMPSE CHAIN:
//   qm_next = (U0/S0)@C[0] + (U1/S1)@C[1],  C = Wmh_m @ Wq  (precomputed)
// removes the per-round Wmh GEMM stage (2 syncs + LDS round) from the
// 65-round allreduce ring; Wmh_lds eliminated. No lambdas.

#define Bb 16
#define Nn 1000
#define Hh 128
#define Ss 16
#define TPB 1024
#define NW 16                 // waves per block
#define NB 16                 // blocks per group
#define ROWS 63               // rows per block
#define TPT (Nn * Bb * Hh)    // elems per projection tensor slot: 2,048,000

// hmean slot: [g][c][132]
#define PPART(g, c) (((size_t)(g)*NB + (size_t)(c)) * 132)
// allreduce accumulator: [buf][g][272]:
//   [0]=S0 [4..131]=U0 ; [132]=S1 [136..263]=U1 ; [264..265]=u64 argmax key
#define ABUF(buf, g) (((size_t)(buf)*16 + (size_t)(g)) * 272)
// C matrices: slots of 256x128 f32: 0,1 = Wmh@Wq3 (m0,m1); 2,3 = Wmh@Wq4;
// 4 = Wmh@Wq2
#define CSLOT 32768

typedef float f32x4 __attribute__((ext_vector_type(4)));
#define NTL(p) __builtin_nontemporal_load((const f32x4*)(p))

__device__ __forceinline__ void red5_2(float& a, float& b) {
#pragma unroll
  for (int m = 1; m <= 16; m <<= 1) {
    a += __shfl_xor(a, m, 64);
    b += __shfl_xor(b, m, 64);
  }
}
__device__ __forceinline__ void red5_4(float& a, float& b, float& c, float& d) {
#pragma unroll
  for (int m = 1; m <= 16; m <<= 1) {
    a += __shfl_xor(a, m, 64);
    b += __shfl_xor(b, m, 64);
    c += __shfl_xor(c, m, 64);
    d += __shfl_xor(d, m, 64);
  }
}
__device__ __forceinline__ float tanh_fast(float x) {
  const float xc = fminf(fmaxf(x, -10.f), 10.f);
  const float e = __expf(xc + xc);
  return (e - 1.f) * __builtin_amdgcn_rcpf(e + 1.f);
}
__device__ __forceinline__ float dot4t(const f32x4 q, const f32x4 r, const f32x4 v) {
  return tanh_fast(q[0] + r[0]) * v[0] + tanh_fast(q[1] + r[1]) * v[1] +
         tanh_fast(q[2] + r[2]) * v[2] + tanh_fast(q[3] + r[3]) * v[3];
}
__device__ __forceinline__ float aload(const float* p) {
  return __hip_atomic_load(p, __ATOMIC_RELAXED, __HIP_MEMORY_SCOPE_AGENT);
}
__device__ __forceinline__ void astore(float* p, float v) {
  __hip_atomic_store(p, v, __ATOMIC_RELAXED, __HIP_MEMORY_SCOPE_AGENT);
}
__device__ __forceinline__ void gbar(int* fl, int c, int p, int tid, int lane) {
  __syncthreads();
  if (tid < 64) {
    if (lane == 0)
      __hip_atomic_store(&fl[c * 32], p, __ATOMIC_RELEASE, __HIP_MEMORY_SCOPE_AGENT);
    int v = p;
    while (true) {
      if (lane < NB)
        v = __hip_atomic_load(&fl[lane * 32], __ATOMIC_RELAXED, __HIP_MEMORY_SCOPE_AGENT);
      if (__all(v >= p)) break;
    }
  }
  __syncthreads();
}

// ---------------------------------------------------------------- projections
__global__ __launch_bounds__(256) void ptr1_proj_kernel(
    const float* __restrict__ enc,
    const float* __restrict__ Wref1, const float* __restrict__ Vec1,
    const float* __restrict__ Wref3, const float* __restrict__ Vec3,
    const float* __restrict__ Wref4, const float* __restrict__ Vec4,
    const float* __restrict__ Wref2,
    float* __restrict__ outp) {
  __shared__ float At[128][64];
  __shared__ float Bs[128][64];
  const int rt = blockIdx.x;
  const int wy = blockIdx.y;
  const int mat = wy >> 1;
  const int ch = wy & 1;
  const int tid = threadIdx.x;

  const float* W;
  switch (mat >> 1) {
    case 0: W = Wref1; break;
    case 1: W = Vec1;  break;
    case 2: W = Wref3; break;
    case 3: W = Vec3;  break;
    case 4: W = Wref4; break;
    case 5: W = Vec4;  break;
    default: W = Wref2; break;
  }
  if (mat < 12) W += (size_t)(mat & 1) * (128 * 128);

  const float* asrc = enc + (size_t)rt * 64 * 128;
  for (int f = tid; f < 64 * 32; f += 256) {
    const int r = f >> 5, k4 = (f & 31) << 2;
    const float4 v = *(const float4*)(asrc + (size_t)r * 128 + k4);
    At[k4 + 0][r] = v.x; At[k4 + 1][r] = v.y;
    At[k4 + 2][r] = v.z; At[k4 + 3][r] = v.w;
  }
  for (int f = tid; f < 128 * 16; f += 256) {
    const int k = f >> 4, c4 = (f & 15) << 2;
    *(float4*)&Bs[k][c4] = *(const float4*)(W + (size_t)k * 128 + ch * 64 + c4);
  }
  __syncthreads();

  const int tx = tid & 15, ty = tid >> 4;
  float acc[4][4] = {{0.f}};
  for (int k = 0; k < 128; ++k) {
    const float4 a = *(const float4*)&At[k][ty * 4];
    const float4 b = *(const float4*)&Bs[k][tx * 4];
    acc[0][0] += a.x * b.x; acc[0][1] += a.x * b.y; acc[0][2] += a.x * b.z; acc[0][3] += a.x * b.w;
    acc[1][0] += a.y * b.x; acc[1][1] += a.y * b.y; acc[1][2] += a.y * b.z; acc[1][3] += a.y * b.w;
    acc[2][0] += a.z * b.x; acc[2][1] += a.z * b.y; acc[2][2] += a.z * b.z; acc[2][3] += a.z * b.w;
    acc[3][0] += a.w * b.x; acc[3][1] += a.w * b.y; acc[3][2] += a.w * b.z; acc[3][3] += a.w * b.w;
  }
  float* dst = outp + (size_t)mat * TPT + ((size_t)rt * 64 + ty * 4) * 128 + ch * 64 + tx * 4;
  for (int i = 0; i < 4; ++i) {
    float4 v; v.x = acc[i][0]; v.y = acc[i][1]; v.z = acc[i][2]; v.w = acc[i][3];
    *(float4*)(dst + (size_t)i * 128) = v;
  }
}

// ---------------------------------------------- C = Wmh @ {Wq3,Wq4,Wq2}
__global__ __launch_bounds__(256) void ptr1_cmat_kernel(
    const float* __restrict__ Wmh, const float* __restrict__ Wq3,
    const float* __restrict__ Wq4, const float* __restrict__ Wq2,
    float* __restrict__ cout) {
  __shared__ float At[128][64];
  __shared__ float Bs[128][64];
  const int rt = blockIdx.x;     // 0..3 row tiles of 64 over Wmh's 256 rows
  const int wy = blockIdx.y;     // 0..9
  const int s = wy >> 1;         // 0..4 slot
  const int ch = wy & 1;
  const int tid = threadIdx.x;

  const float* W = (s < 2) ? (Wq3 + (size_t)(s & 1) * 16384)
                 : (s < 4) ? (Wq4 + (size_t)((s - 2) & 1) * 16384)
                           : Wq2;

  const float* asrc = Wmh + (size_t)rt * 64 * 128;
  for (int f = tid; f < 64 * 32; f += 256) {
    const int r = f >> 5, k4 = (f & 31) << 2;
    const float4 v = *(const float4*)(asrc + (size_t)r * 128 + k4);
    At[k4 + 0][r] = v.x; At[k4 + 1][r] = v.y;
    At[k4 + 2][r] = v.z; At[k4 + 3][r] = v.w;
  }
  for (int f = tid; f < 128 * 16; f += 256) {
    const int k = f >> 4, c4 = (f & 15) << 2;
    *(float4*)&Bs[k][c4] = *(const float4*)(W + (size_t)k * 128 + ch * 64 + c4);
  }
  __syncthreads();

  const int tx = tid & 15, ty = tid >> 4;
  float acc[4][4] = {{0.f}};
  for (int k = 0; k < 128; ++k) {
    const float4 a = *(const float4*)&At[k][ty * 4];
    const float4 b = *(const float4*)&Bs[k][tx * 4];
    acc[0][0] += a.x * b.x; acc[0][1] += a.x * b.y; acc[0][2] += a.x * b.z; acc[0][3] += a.x * b.w;
    acc[1][0] += a.y * b.x; acc[1][1] += a.y * b.y; acc[1][2] += a.y * b.z; acc[1][3] += a.y * b.w;
    acc[2][0] += a.z * b.x; acc[2][1] += a.z * b.y; acc[2][2] += a.z * b.z; acc[2][3] += a.z * b.w;
    acc[3][0] += a.w * b.x; acc[3][1] += a.w * b.y; acc[3][2] += a.w * b.z; acc[3][3] += a.w * b.w;
  }
  float* dst = cout + (size_t)s * CSLOT + ((size_t)rt * 64 + ty * 4) * 128 + ch * 64 + tx * 4;
  for (int i = 0; i < 4; ++i) {
    float4 v; v.x = acc[i][0]; v.y = acc[i][1]; v.z = acc[i][2]; v.w = acc[i][3];
    *(float4*)(dst + (size_t)i * 128) = v;
  }
}

// ------------------------------------------------------------------- decode
__global__ __launch_bounds__(1024, 4) void ptr1_decode_kernel(
    const float* __restrict__ enc, const float* __restrict__ mask0,
    const float* __restrict__ Wq1, const float* __restrict__ Wq2,
    const float* __restrict__ Vec2, const float* __restrict__ dec_inp,
    const float* __restrict__ proj, const float* __restrict__ cmat,
    float* __restrict__ partials, float* __restrict__ accum,
    int* __restrict__ flags, float* __restrict__ out) {
  const int g = blockIdx.x & 15;   // XCD-affinity: group g -> XCD g%8
  const int c = blockIdx.x >> 4;
  const int tid = threadIdx.x;
  const int wv = tid >> 6;
  const int lane = tid & 63;
  const int half = lane >> 5;
  const int hl = lane & 31;
  const int h0 = hl << 2;
  const int start = c * ROWS;
  const int cnt = min(ROWS, Nn - start);
  const int jrow = wv * 2 + half;
  const int j2 = jrow + 32;
  const bool a2 = j2 < cnt;
  const int j2c = a2 ? j2 : jrow;
  int* fl = flags + g * (16 * 32);

  __shared__ __align__(16) float hmean[128];
  __shared__ __align__(16) float qprev[128];
  __shared__ __align__(16) float base1[256];
  __shared__ __align__(16) float qm[2][128];
  __shared__ __align__(16) float gfraw[256];
  __shared__ __align__(16) float vecl[128];
  __shared__ __align__(16) float wpart[NW][2][132];
  __shared__ __align__(16) float qpart[4][256];
  __shared__ __align__(16) float mpart[8][128];
  __shared__ float maskl[64];
  __shared__ float ulocal[64];
  __shared__ int sel_sh;
  __shared__ float logZ_sh;

  float* qmf = &qm[0][0];
  if (tid < 128) vecl[tid] = Vec2[tid];
  for (int j = tid; j < cnt; j += TPB) maskl[j] = mask0[(size_t)g * Nn + start + j];

  const size_t o1 = (size_t)jrow * Hh;
  const size_t o2 = (size_t)j2c * Hh;
  const size_t rowb = ((size_t)g * Nn + start) * Hh + h0;
  const float* pb = proj + rowb;
  const float* C3 = cmat;                  // slots 0,1
  const float* C4 = cmat + 2 * CSLOT;      // slots 2,3
  const float* C2 = cmat + 4 * CSLOT;      // slot 4

  // ---- phase 0: h_mean, then base1 = hmean @ Wq1_top (once) ----
  {
    const float* eb = enc + rowb;
    const float4 eA = *(const float4*)(eb + o1);
    const float4 eB = *(const float4*)(eb + o2);
    float4 a;
    a.x = eA.x + (a2 ? eB.x : 0.f); a.y = eA.y + (a2 ? eB.y : 0.f);
    a.z = eA.z + (a2 ? eB.z : 0.f); a.w = eA.w + (a2 ? eB.w : 0.f);
    a.x += __shfl_xor(a.x, 32, 64); a.y += __shfl_xor(a.y, 32, 64);
    a.z += __shfl_xor(a.z, 32, 64); a.w += __shfl_xor(a.w, 32, 64);
    if (half == 0) *(float4*)&wpart[wv][0][4 + h0] = a;
    __syncthreads();
    if (tid < 128) {
      float s = 0.f;
      for (int w = 0; w < NW; ++w) s += wpart[w][0][4 + tid];
      astore(&partials[PPART(g, c) + 4 + tid], s);
    }
    gbar(fl, c, 1, tid, lane);
    if (tid < 128) {
      float s = 0.f;
#pragma unroll 8
      for (int cc = 0; cc < NB; ++cc) s += aload(&partials[PPART(g, cc) + 4 + tid]);
      hmean[tid] = s * (1.0f / (float)Nn);
    }
    if (tid >= 128 && tid < 256) qprev[tid - 128] = dec_inp[tid - 128];
    __syncthreads();
    {  // base1[m][h] = sum_{i<128} hmean[i] * Wq1[m][i][h]
      const int o = tid & 255, part = tid >> 8;
      const int m = o >> 7, h = o & 127;
      const float* wp = Wq1 + (size_t)m * 256 * 128 + (size_t)(part * 32) * 128 + h;
      const float* qc = hmean + part * 32;
      float acc = 0.f;
#pragma unroll 16
      for (int i = 0; i < 32; ++i) acc += qc[i] * wp[(size_t)i * 128];
      qpart[part][o] = acc;
    }
    __syncthreads();
    if (tid < 256)
      base1[tid] = qpart[0][tid] + qpart[1][tid] + qpart[2][tid] + qpart[3][tid];
    __syncthreads();
  }

  int p = 2;
  for (int step = 0; step < Ss; ++step) {
    // ================= Phase A (glimpse 1) =================
    const float* r0pA = pb + (size_t)0 * TPT;
    const float* r1pA = pb + (size_t)1 * TPT;
    const float* v0pA = pb + (size_t)2 * TPT;
    const float* v1pA = pb + (size_t)3 * TPT;
    {
      const f32x4 r0A = NTL(r0pA + o1), r0B = NTL(r0pA + o2);
      const f32x4 r1A = NTL(r1pA + o1), r1B = NTL(r1pA + o2);
      const f32x4 v0A = NTL(v0pA + o1), v0B = NTL(v0pA + o2);
      const f32x4 v1A = NTL(v1pA + o1), v1B = NTL(v1pA + o2);
      __builtin_amdgcn_sched_barrier(0);
      {  // q-proj: base1 + qprev @ Wq1_bot
        const int o = tid & 255, part = tid >> 8;
        const int m = o >> 7, h = o & 127;
        const float* wp = Wq1 + (size_t)m * 256 * 128 + (size_t)(128 + part * 32) * 128 + h;
        const float* qc = qprev + part * 32;
        float acc = 0.f;
#pragma unroll 16
        for (int i = 0; i < 32; ++i) acc += qc[i] * wp[(size_t)i * 128];
        qpart[part][o] = acc;
      }
      __syncthreads();
      if (tid < 256)
        qmf[tid] = qpart[0][tid] + qpart[1][tid] + qpart[2][tid] + qpart[3][tid] + base1[tid];
      __syncthreads();

      const f32x4 qa = *(const f32x4*)&qm[0][h0];
      const f32x4 qb = *(const f32x4*)&qm[1][h0];
      const float mlA = maskl[jrow], mlB = maskl[j2c];
      float s0A = dot4t(qa, r0A, v0A), s1A = dot4t(qb, r1A, v1A);
      float s0B = dot4t(qa, r0B, v0B), s1B = dot4t(qb, r1B, v1B);
      red5_4(s0A, s1A, s0B, s1B);
      s0A = 10.f * tanh_fast(s0A) - 1e8f * mlA;
      s1A = 10.f * tanh_fast(s1A) - 1e8f * mlA;
      s0B = 10.f * tanh_fast(s0B) - 1e8f * mlB;
      s1B = 10.f * tanh_fast(s1B) - 1e8f * mlB;
      const float e0A = __expf(s0A - 10.f), e1A = __expf(s1A - 10.f);
      const float e0B = a2 ? __expf(s0B - 10.f) : 0.f;
      const float e1B = a2 ? __expf(s1B - 10.f) : 0.f;
      float S0 = e0A + e0B, S1 = e1A + e1B;
      f32x4 g0 = r0A * e0A + r0B * e0B;
      f32x4 g1 = r1A * e1A + r1B * e1B;
      S0 += __shfl_xor(S0, 32, 64); S1 += __shfl_xor(S1, 32, 64);
      g0[0] += __shfl_xor(g0[0], 32, 64); g0[1] += __shfl_xor(g0[1], 32, 64);
      g0[2] += __shfl_xor(g0[2], 32, 64); g0[3] += __shfl_xor(g0[3], 32, 64);
      g1[0] += __shfl_xor(g1[0], 32, 64); g1[1] += __shfl_xor(g1[1], 32, 64);
      g1[2] += __shfl_xor(g1[2], 32, 64); g1[3] += __shfl_xor(g1[3], 32, 64);
      if (half == 0) {
        *(f32x4*)&wpart[wv][0][4 + h0] = g0;
        *(f32x4*)&wpart[wv][1][4 + h0] = g1;
        if (hl == 0) { wpart[wv][0][0] = S0; wpart[wv][1][0] = S1; }
      }
      __syncthreads();
      float* ab = accum + ABUF(p & 3, g);
      float* zb = accum + ABUF((p + 1) & 3, g);
      if (tid < 256) {
        const int m = tid >> 7, h = tid & 127;
        float gs = 0.f;
        for (int w = 0; w < NW; ++w) gs += wpart[w][m][4 + h];
        unsafeAtomicAdd(&ab[m * 132 + 4 + h], gs);
        if (h == 0) {
          float ss = 0.f;
          for (int w = 0; w < NW; ++w) ss += wpart[w][m][0];
          unsafeAtomicAdd(&ab[m * 132], ss);
        }
      } else if (tid >= 512 && tid < 529) {
        const int idx = c * 17 + (tid - 512);
        if (idx < 272) astore(&zb[idx], 0.f);
      }
      gbar(fl, c, p, tid, lane);
      p++;
      // tail: scaled read + C3 gemm -> qm for glimpse 2
      if (tid < 256) {
        const int mm = tid >> 7;
        const float Sr = aload(&ab[mm * 132]);
        gfraw[tid] = aload(&ab[mm * 132 + 4 + (tid & 127)]) / Sr;
      }
      __syncthreads();
    }
    {
      const int o = tid & 255, part = tid >> 8;
      const int m = o >> 7, h = o & 127;
      const float* cp = C3 + (size_t)m * CSLOT + (size_t)(part * 64) * 128 + h;
      const float* gc = gfraw + part * 64;
      float acc = 0.f;
#pragma unroll 16
      for (int i = 0; i < 64; ++i) acc += gc[i] * cp[(size_t)i * 128];
      qpart[part][o] = acc;
    }
    __syncthreads();
    if (tid < 256)
      qmf[tid] = qpart[0][tid] + qpart[1][tid] + qpart[2][tid] + qpart[3][tid];
    __syncthreads();

    // ================= Phase B (glimpse 2) =================
    const float* r0pB = pb + (size_t)4 * TPT;
    const float* r1pB = pb + (size_t)5 * TPT;
    const float* v0pB = pb + (size_t)6 * TPT;
    const float* v1pB = pb + (size_t)7 * TPT;
    {
      const f32x4 r0A = NTL(r0pB + o1), r0B = NTL(r0pB + o2);
      const f32x4 r1A = NTL(r1pB + o1), r1B = NTL(r1pB + o2);
      const f32x4 v0A = NTL(v0pB + o1), v0B = NTL(v0pB + o2);
      const f32x4 v1A = NTL(v1pB + o1), v1B = NTL(v1pB + o2);
      __builtin_amdgcn_sched_barrier(0);
      const f32x4 qa = *(const f32x4*)&qm[0][h0];
      const f32x4 qb = *(const f32x4*)&qm[1][h0];
      const float mlA = maskl[jrow], mlB = maskl[j2c];
      float s0A = dot4t(qa, r0A, v0A), s1A = dot4t(qb, r1A, v1A);
      float s0B = dot4t(qa, r0B, v0B), s1B = dot4t(qb, r1B, v1B);
      red5_4(s0A, s1A, s0B, s1B);
      s0A = 10.f * tanh_fast(s0A) - 1e8f * mlA;
      s1A = 10.f * tanh_fast(s1A) - 1e8f * mlA;
      s0B = 10.f * tanh_fast(s0B) - 1e8f * mlB;
      s1B = 10.f * tanh_fast(s1B) - 1e8f * mlB;
      const float e0A = __expf(s0A - 10.f), e1A = __expf(s1A - 10.f);
      const float e0B = a2 ? __expf(s0B - 10.f) : 0.f;
      const float e1B = a2 ? __expf(s1B - 10.f) : 0.f;
      float S0 = e0A + e0B, S1 = e1A + e1B;
      f32x4 g0 = r0A * e0A + r0B * e0B;
      f32x4 g1 = r1A * e1A + r1B * e1B;
      S0 += __shfl_xor(S0, 32, 64); S1 += __shfl_xor(S1, 32, 64);
      g0[0] += __shfl_xor(g0[0], 32, 64); g0[1] += __shfl_xor(g0[1], 32, 64);
      g0[2] += __shfl_xor(g0[2], 32, 64); g0[3] += __shfl_xor(g0[3], 32, 64);
      g1[0] += __shfl_xor(g1[0], 32, 64); g1[1] += __shfl_xor(g1[1], 32, 64);
      g1[2] += __shfl_xor(g1[2], 32, 64); g1[3] += __shfl_xor(g1[3], 32, 64);
      if (half == 0) {
        *(f32x4*)&wpart[wv][0][4 + h0] = g0;
        *(f32x4*)&wpart[wv][1][4 + h0] = g1;
        if (hl == 0) { wpart[wv][0][0] = S0; wpart[wv][1][0] = S1; }
      }
      __syncthreads();
      float* ab = accum + ABUF(p & 3, g);
      float* zb = accum + ABUF((p + 1) & 3, g);
      if (tid < 256) {
        const int m = tid >> 7, h = tid & 127;
        float gs = 0.f;
        for (int w = 0; w < NW; ++w) gs += wpart[w][m][4 + h];
        unsafeAtomicAdd(&ab[m * 132 + 4 + h], gs);
        if (h == 0) {
          float ss = 0.f;
          for (int w = 0; w < NW; ++w) ss += wpart[w][m][0];
          unsafeAtomicAdd(&ab[m * 132], ss);
        }
      } else if (tid >= 512 && tid < 529) {
        const int idx = c * 17 + (tid - 512);
        if (idx < 272) astore(&zb[idx], 0.f);
      }
      gbar(fl, c, p, tid, lane);
      p++;
      if (tid < 256) {
        const int mm = tid >> 7;
        const float Sr = aload(&ab[mm * 132]);
        gfraw[tid] = aload(&ab[mm * 132 + 4 + (tid & 127)]) / Sr;
      }
      __syncthreads();
    }
    {
      const int o = tid & 255, part = tid >> 8;
      const int m = o >> 7, h = o & 127;
      const float* cp = C4 + (size_t)m * CSLOT + (size_t)(part * 64) * 128 + h;
      const float* gc = gfraw + part * 64;
      float acc = 0.f;
#pragma unroll 16
      for (int i = 0; i < 64; ++i) acc += gc[i] * cp[(size_t)i * 128];
      qpart[part][o] = acc;
    }
    __syncthreads();
    if (tid < 256)
      qmf[tid] = qpart[0][tid] + qpart[1][tid] + qpart[2][tid] + qpart[3][tid];
    __syncthreads();

    // ================= Phase C (glimpse 3) =================
    const float* r0pC = pb + (size_t)8 * TPT;
    const float* r1pC = pb + (size_t)9 * TPT;
    const float* v0pC = pb + (size_t)10 * TPT;
    const float* v1pC = pb + (size_t)11 * TPT;
    {
      const f32x4 r0A = NTL(r0pC + o1), r0B = NTL(r0pC + o2);
      const f32x4 r1A = NTL(r1pC + o1), r1B = NTL(r1pC + o2);
      const f32x4 v0A = NTL(v0pC + o1), v0B = NTL(v0pC + o2);
      const f32x4 v1A = NTL(v1pC + o1), v1B = NTL(v1pC + o2);
      __builtin_amdgcn_sched_barrier(0);
      const f32x4 qa = *(const f32x4*)&qm[0][h0];
      const f32x4 qb = *(const f32x4*)&qm[1][h0];
      const float mlA = maskl[jrow], mlB = maskl[j2c];
      float s0A = dot4t(qa, r0A, v0A), s1A = dot4t(qb, r1A, v1A);
      float s0B = dot4t(qa, r0B, v0B), s1B = dot4t(qb, r1B, v1B);
      red5_4(s0A, s1A, s0B, s1B);
      s0A = 10.f * tanh_fast(s0A) - 1e8f * mlA;
      s1A = 10.f * tanh_fast(s1A) - 1e8f * mlA;
      s0B = 10.f * tanh_fast(s0B) - 1e8f * mlB;
      s1B = 10.f * tanh_fast(s1B) - 1e8f * mlB;
      const float e0A = __expf(s0A - 10.f), e1A = __expf(s1A - 10.f);
      const float e0B = a2 ? __expf(s0B - 10.f) : 0.f;
      const float e1B = a2 ? __expf(s1B - 10.f) : 0.f;
      float S0 = e0A + e0B, S1 = e1A + e1B;
      f32x4 g0 = r0A * e0A + r0B * e0B;
      f32x4 g1 = r1A * e1A + r1B * e1B;
      S0 += __shfl_xor(S0, 32, 64); S1 += __shfl_xor(S1, 32, 64);
      g0[0] += __shfl_xor(g0[0], 32, 64); g0[1] += __shfl_xor(g0[1], 32, 64);
      g0[2] += __shfl_xor(g0[2], 32, 64); g0[3] += __shfl_xor(g0[3], 32, 64);
      g1[0] += __shfl_xor(g1[0], 32, 64); g1[1] += __shfl_xor(g1[1], 32, 64);
      g1[2] += __shfl_xor(g1[2], 32, 64); g1[3] += __shfl_xor(g1[3], 32, 64);
      if (half == 0) {
        *(f32x4*)&wpart[wv][0][4 + h0] = g0;
        *(f32x4*)&wpart[wv][1][4 + h0] = g1;
        if (hl == 0) { wpart[wv][0][0] = S0; wpart[wv][1][0] = S1; }
      }
      __syncthreads();
      float* ab = accum + ABUF(p & 3, g);
      float* zb = accum + ABUF((p + 1) & 3, g);
      if (tid < 256) {
        const int m = tid >> 7, h = tid & 127;
        float gs = 0.f;
        for (int w = 0; w < NW; ++w) gs += wpart[w][m][4 + h];
        unsafeAtomicAdd(&ab[m * 132 + 4 + h], gs);
        if (h == 0) {
          float ss = 0.f;
          for (int w = 0; w < NW; ++w) ss += wpart[w][m][0];
          unsafeAtomicAdd(&ab[m * 132], ss);
        }
      } else if (tid >= 512 && tid < 529) {
        const int idx = c * 17 + (tid - 512);
        if (idx < 272) astore(&zb[idx], 0.f);
      }
      gbar(fl, c, p, tid, lane);
      p++;
      if (tid < 256) {
        const int mm = tid >> 7;
        const float Sr = aload(&ab[mm * 132]);
        gfraw[tid] = aload(&ab[mm * 132 + 4 + (tid & 127)]) / Sr;
      }
      __syncthreads();
    }
    {  // pointer q via C2: 128 outputs, 8-way over i (seg 32)
      const int h = tid & 127, part = tid >> 7;
      const float* cp = C2 + (size_t)(part * 32) * 128 + h;
      const float* gc = gfraw + part * 32;
      float acc = 0.f;
#pragma unroll 16
      for (int i = 0; i < 32; ++i) acc += gc[i] * cp[(size_t)i * 128];
      mpart[part][h] = acc;
    }
    __syncthreads();
    if (tid < 128) {
      float acc = 0.f;
      for (int w = 0; w < 8; ++w) acc += mpart[w][tid];
      qm[0][tid] = acc;
    }
    __syncthreads();

    // ================= Phase D (pointer) =================
    const float* r2p = pb + (size_t)12 * TPT;
    {
      const f32x4 rrA = NTL(r2p + o1);
      const f32x4 rrB = NTL(r2p + o2);
      __builtin_amdgcn_sched_barrier(0);
      const f32x4 q2 = *(const f32x4*)&qm[0][h0];
      const f32x4 vz = *(const f32x4*)&vecl[h0];
      float upA = dot4t(q2, rrA, vz);
      float upB = dot4t(q2, rrB, vz);
      red5_2(upA, upB);
      const float mlA = maskl[jrow], mlB = maskl[j2c];
      const float uA = 10.f * tanh_fast(upA) - 1e8f * mlA;
      const float uB = a2 ? (10.f * tanh_fast(upB) - 1e8f * mlB) : -3.0e38f;
      if (hl == 0) {
        ulocal[jrow] = uA;
        if (a2) ulocal[j2] = uB;
      }
      float Sv = __expf(uA - 10.f) + (a2 ? __expf(uB - 10.f) : 0.f);
      float um = uA; int ui = start + jrow;
      if (a2 && uB > um) { um = uB; ui = start + j2; }
      Sv += __shfl_xor(Sv, 32, 64);
      const float um2 = __shfl_xor(um, 32, 64);
      const int ui2 = __shfl_xor(ui, 32, 64);
      if (um2 > um || (um2 == um && ui2 < ui)) { um = um2; ui = ui2; }
      if (lane == 0) {
        wpart[wv][0][0] = Sv; wpart[wv][0][1] = um;
        wpart[wv][0][2] = __int_as_float(ui);
      }
    }
    __syncthreads();
    float* ab = accum + ABUF(p & 3, g);
    float* zb = accum + ABUF((p + 1) & 3, g);
    if (tid == 0) {
      float St = 0.f, bm = -3.0e38f; int bi = 0x7fffffff;
      for (int ww = 0; ww < NW; ++ww) {
        St += wpart[ww][0][0];
        const float m2 = wpart[ww][0][1];
        const int i2 = __float_as_int(wpart[ww][0][2]);
        if (m2 > bm || (m2 == bm && i2 < bi)) { bm = m2; bi = i2; }
      }
      unsigned ob = __float_as_uint(bm);
      ob = (ob & 0x80000000u) ? ~ob : (ob | 0x80000000u);
      const unsigned long long key =
          ((unsigned long long)ob << 32) | (0xFFFFFFFFu - (unsigned)bi);
      unsafeAtomicAdd(&ab[0], St);
      atomicMax((unsigned long long*)&ab[264], key);
    } else if (tid >= 512 && tid < 529) {
      const int idx = c * 17 + (tid - 512);
      if (idx < 272) astore(&zb[idx], 0.f);
    }
    gbar(fl, c, p, tid, lane);
    p++;
    if (tid == 0) {
      const float St = aload(&ab[0]);
      const unsigned long long key = __hip_atomic_load(
          (const unsigned long long*)&ab[264], __ATOMIC_RELAXED,
          __HIP_MEMORY_SCOPE_AGENT);
      sel_sh = (int)(0xFFFFFFFFu - (unsigned)(key & 0xFFFFFFFFu));
      logZ_sh = 10.f + __logf(St);
    }
    __syncthreads();
    const int sel = sel_sh;
    const float lz = logZ_sh;
    if (tid < 128)
      qprev[tid] = enc[((size_t)g * Nn + sel) * Hh + tid];
    for (int j = tid; j < cnt; j += TPB)
      out[(size_t)step * (Bb * Nn) + (size_t)g * Nn + start + j] = ulocal[j] - lz;
    if (c == 0 && tid == 0)
      out[(size_t)Ss * Bb * Nn + (size_t)step * Bb + g] = (float)sel;
    if (tid == 0 && sel >= start && sel < start + cnt) maskl[sel - start] = 1.0f;
    __syncthreads();
  }
}

// -------------------------------------------------------------------- launch
extern "C" void kernel_launch(void* const* d_in, const int* in_sizes, int n_in,
                              void* d_out, int out_size, void* d_ws, size_t ws_size,
                              hipStream_t stream) {
  const float* enc     = (const float*)d_in[0];
  const float* mask0   = (const float*)d_in[1];
  const float* Wq1     = (const float*)d_in[2];
  const float* Wref1   = (const float*)d_in[3];
  const float* Vec1    = (const float*)d_in[4];
  const float* Wq3     = (const float*)d_in[5];
  const float* Wref3   = (const float*)d_in[6];
  const float* Vec3    = (const float*)d_in[7];
  const float* Wq4     = (const float*)d_in[8];
  const float* Wref4   = (const float*)d_in[9];
  const float* Vec4    = (const float*)d_in[10];
  const float* Wmh     = (const float*)d_in[11];
  const float* Wq2     = (const float*)d_in[12];
  const float* Wref2   = (const float*)d_in[13];
  const float* Vec2    = (const float*)d_in[14];
  const float* dec_inp = (const float*)d_in[15];
  float* out = (float*)d_out;

  char* ws = (char*)d_ws;
  int* flags      = (int*)ws;                          // 32,768 B
  float* accum    = (float*)(ws + 32768);              // 69,632 B
  float* partials = (float*)(ws + 102400);             // 16*16*132*4 = 135,168 B
  float* cmat     = (float*)(ws + 102400 + 135168);    // 5*32768*4 = 655,360 B
  float* proj     = (float*)(ws + 102400 + 135168 + 655360);  // 13*2,048,000 f32

  hipMemsetAsync(ws, 0, 102400, stream);  // zero flags + accum

  dim3 pg(250, 26);
  ptr1_proj_kernel<<<pg, 256, 0, stream>>>(enc, Wref1, Vec1, Wref3, Vec3,
                                           Wref4, Vec4, Wref2, proj);
  ptr1_cmat_kernel<<<dim3(4, 10), 256, 0, stream>>>(Wmh, Wq3, Wq4, Wq2, cmat);

  void* args[] = {(void*)&enc,  (void*)&mask0, (void*)&Wq1, (void*)&Wq2,
                  (void*)&Vec2, (void*)&dec_inp, (void*)&proj, (void*)&cmat,
                  (void*)&partials, (void*)&accum, (void*)&flags, (void*)&out};
  hipLaunchCooperativeKernel((const void*)ptr1_decode_kernel, dim3(256),
                             dim3(1024), args, 0, stream);
}

// Round 16
// 942.938 us; speedup vs baseline: 1.5419x; 1.5419x over previous
//
#include <hip/hip_runtime.h>

// PtrNet greedy decode, B=16, N=1000, H=128, M=2, 16 steps.
// CHAMPION (R13, 944us): R8 structure + XCD-affinity mapping (g=blk&15,
// c=blk>>4 -> each group's 16 blocks on one XCD; barrier/allreduce lines
// XCD-local). Flag barriers, atomicAdd allreduce, Wmh in LDS, fused
// atomicMax pointer argmax, NT proj streaming, no lambdas.
// R14's fused-C-chain regressed (global operand on post-barrier critical
// path); restored verbatim.

#define Bb 16
#define Nn 1000
#define Hh 128
#define Ss 16
#define TPB 1024
#define NW 16                 // waves per block
#define NB 16                 // blocks per group
#define ROWS 63               // rows per block
#define TPT (Nn * Bb * Hh)    // elems per projection tensor slot: 2,048,000

// hmean-phase slot: [par][g][c][m][132]
#define PPART(par, g, c, m) \
  ((((size_t)(par)*16 + (size_t)(g))*NB + (size_t)(c))*2 + (size_t)(m))*132
// allreduce accumulator: [buf][g][272]:
//   [0]=S0 [4..131]=U0 ; [132]=S1 [136..263]=U1 ; [264..265]=u64 argmax key
#define ABUF(buf, g) (((size_t)(buf)*16 + (size_t)(g)) * 272)

typedef float f32x4 __attribute__((ext_vector_type(4)));
#define NTL(p) __builtin_nontemporal_load((const f32x4*)(p))

__device__ __forceinline__ void red5_2(float& a, float& b) {
#pragma unroll
  for (int m = 1; m <= 16; m <<= 1) {
    a += __shfl_xor(a, m, 64);
    b += __shfl_xor(b, m, 64);
  }
}
__device__ __forceinline__ void red5_4(float& a, float& b, float& c, float& d) {
#pragma unroll
  for (int m = 1; m <= 16; m <<= 1) {
    a += __shfl_xor(a, m, 64);
    b += __shfl_xor(b, m, 64);
    c += __shfl_xor(c, m, 64);
    d += __shfl_xor(d, m, 64);
  }
}

// fast tanh: (e-1)/(e+1), e=exp(2x), clamped so v_exp never overflows.
__device__ __forceinline__ float tanh_fast(float x) {
  const float xc = fminf(fmaxf(x, -10.f), 10.f);
  const float e = __expf(xc + xc);
  return (e - 1.f) * __builtin_amdgcn_rcpf(e + 1.f);
}
__device__ __forceinline__ float dot4t(const f32x4 q, const f32x4 r, const f32x4 v) {
  return tanh_fast(q[0] + r[0]) * v[0] + tanh_fast(q[1] + r[1]) * v[1] +
         tanh_fast(q[2] + r[2]) * v[2] + tanh_fast(q[3] + r[3]) * v[3];
}

// agent-coherent access (coherence point; bypasses stale L1/L2)
__device__ __forceinline__ float aload(const float* p) {
  return __hip_atomic_load(p, __ATOMIC_RELAXED, __HIP_MEMORY_SCOPE_AGENT);
}
__device__ __forceinline__ void astore(float* p, float v) {
  __hip_atomic_store(p, v, __ATOMIC_RELAXED, __HIP_MEMORY_SCOPE_AGENT);
}

// Flag-array group barrier: block c release-stores monotonic phase id to its
// own 128B-strided flag; wave 0 spins on all NB flags in parallel.
__device__ __forceinline__ void gbar(int* fl, int c, int p, int tid, int lane) {
  __syncthreads();
  if (tid < 64) {
    if (lane == 0)
      __hip_atomic_store(&fl[c * 32], p, __ATOMIC_RELEASE, __HIP_MEMORY_SCOPE_AGENT);
    int v = p;
    while (true) {
      if (lane < NB)
        v = __hip_atomic_load(&fl[lane * 32], __ATOMIC_RELAXED, __HIP_MEMORY_SCOPE_AGENT);
      if (__all(v >= p)) break;
    }
  }
  __syncthreads();
}

// ---------------------------------------------------------------- projections
__global__ __launch_bounds__(256) void ptr1_proj_kernel(
    const float* __restrict__ enc,
    const float* __restrict__ Wref1, const float* __restrict__ Vec1,
    const float* __restrict__ Wref3, const float* __restrict__ Vec3,
    const float* __restrict__ Wref4, const float* __restrict__ Vec4,
    const float* __restrict__ Wref2,
    float* __restrict__ outp) {
  __shared__ float At[128][64];
  __shared__ float Bs[128][64];
  const int rt = blockIdx.x;
  const int wy = blockIdx.y;
  const int mat = wy >> 1;
  const int ch = wy & 1;
  const int tid = threadIdx.x;

  const float* W;
  switch (mat >> 1) {
    case 0: W = Wref1; break;
    case 1: W = Vec1;  break;
    case 2: W = Wref3; break;
    case 3: W = Vec3;  break;
    case 4: W = Wref4; break;
    case 5: W = Vec4;  break;
    default: W = Wref2; break;
  }
  if (mat < 12) W += (size_t)(mat & 1) * (128 * 128);

  const float* asrc = enc + (size_t)rt * 64 * 128;
  for (int f = tid; f < 64 * 32; f += 256) {
    const int r = f >> 5, k4 = (f & 31) << 2;
    const float4 v = *(const float4*)(asrc + (size_t)r * 128 + k4);
    At[k4 + 0][r] = v.x; At[k4 + 1][r] = v.y;
    At[k4 + 2][r] = v.z; At[k4 + 3][r] = v.w;
  }
  for (int f = tid; f < 128 * 16; f += 256) {
    const int k = f >> 4, c4 = (f & 15) << 2;
    *(float4*)&Bs[k][c4] = *(const float4*)(W + (size_t)k * 128 + ch * 64 + c4);
  }
  __syncthreads();

  const int tx = tid & 15, ty = tid >> 4;
  float acc[4][4] = {{0.f}};
  for (int k = 0; k < 128; ++k) {
    const float4 a = *(const float4*)&At[k][ty * 4];
    const float4 b = *(const float4*)&Bs[k][tx * 4];
    acc[0][0] += a.x * b.x; acc[0][1] += a.x * b.y; acc[0][2] += a.x * b.z; acc[0][3] += a.x * b.w;
    acc[1][0] += a.y * b.x; acc[1][1] += a.y * b.y; acc[1][2] += a.y * b.z; acc[1][3] += a.y * b.w;
    acc[2][0] += a.z * b.x; acc[2][1] += a.z * b.y; acc[2][2] += a.z * b.z; acc[2][3] += a.z * b.w;
    acc[3][0] += a.w * b.x; acc[3][1] += a.w * b.y; acc[3][2] += a.w * b.z; acc[3][3] += a.w * b.w;
  }
  float* dst = outp + (size_t)mat * TPT + ((size_t)rt * 64 + ty * 4) * 128 + ch * 64 + tx * 4;
  for (int i = 0; i < 4; ++i) {
    float4 v; v.x = acc[i][0]; v.y = acc[i][1]; v.z = acc[i][2]; v.w = acc[i][3];
    *(float4*)(dst + (size_t)i * 128) = v;
  }
}

// ------------------------------------------------------------------- decode
__global__ __launch_bounds__(1024, 4) void ptr1_decode_kernel(
    const float* __restrict__ enc, const float* __restrict__ mask0,
    const float* __restrict__ Wq1, const float* __restrict__ Wq3,
    const float* __restrict__ Wq4, const float* __restrict__ Wmh,
    const float* __restrict__ Wq2, const float* __restrict__ Vec2,
    const float* __restrict__ dec_inp, const float* __restrict__ proj,
    float* __restrict__ partials, float* __restrict__ accum,
    int* __restrict__ flags, float* __restrict__ out) {
  const int g = blockIdx.x & 15;   // XCD-affinity: group g's 16 blocks are
  const int c = blockIdx.x >> 4;   // blk=c*16+g -> blk%8 = g%8 (one XCD/group)
  const int tid = threadIdx.x;
  const int wv = tid >> 6;
  const int lane = tid & 63;
  const int half = lane >> 5;
  const int hl = lane & 31;
  const int h0 = hl << 2;
  const int start = c * ROWS;
  const int cnt = min(ROWS, Nn - start);
  const int jrow = wv * 2 + half;
  const int j2 = jrow + 32;
  const bool a2 = j2 < cnt;
  const int j2c = a2 ? j2 : jrow;
  int* fl = flags + g * (16 * 32);

  __shared__ float Wmh_lds[256 * 128];     // 131,072 B
  __shared__ __align__(16) float hmean[128];
  __shared__ __align__(16) float qprev[128];
  __shared__ __align__(16) float qcur[128];
  __shared__ __align__(16) float base1[256];
  __shared__ __align__(16) float qm[2][128];
  __shared__ __align__(16) float gfraw[256];
  __shared__ __align__(16) float vecl[128];
  __shared__ __align__(16) float wpart[NW][2][132];
  __shared__ __align__(16) float qpart[4][256];
  __shared__ __align__(16) float mpart[8][128];
  __shared__ float sS[2];
  __shared__ float maskl[64];
  __shared__ float ulocal[64];
  __shared__ int sel_sh;
  __shared__ float logZ_sh;

  {  // preload Wmh into LDS
    float4* wl = (float4*)Wmh_lds;
    const float4* wg = (const float4*)Wmh;
#pragma unroll
    for (int k = 0; k < 8; ++k) wl[tid + k * TPB] = wg[tid + k * TPB];
  }
  if (tid < 128) vecl[tid] = Vec2[tid];
  for (int j = tid; j < cnt; j += TPB) maskl[j] = mask0[(size_t)g * Nn + start + j];

  const size_t o1 = (size_t)jrow * Hh;
  const size_t o2 = (size_t)j2c * Hh;
  const size_t rowb = ((size_t)g * Nn + start) * Hh + h0;
  const float* pb = proj + rowb;

  // ---- phase 0: h_mean, then base1 = hmean @ Wq1_top (once) ----
  {
    const float* eb = enc + rowb;
    const float4 eA = *(const float4*)(eb + o1);
    const float4 eB = *(const float4*)(eb + o2);
    float4 a;
    a.x = eA.x + (a2 ? eB.x : 0.f); a.y = eA.y + (a2 ? eB.y : 0.f);
    a.z = eA.z + (a2 ? eB.z : 0.f); a.w = eA.w + (a2 ? eB.w : 0.f);
    a.x += __shfl_xor(a.x, 32, 64); a.y += __shfl_xor(a.y, 32, 64);
    a.z += __shfl_xor(a.z, 32, 64); a.w += __shfl_xor(a.w, 32, 64);
    if (half == 0) *(float4*)&wpart[wv][0][4 + h0] = a;
    __syncthreads();
    if (tid < 128) {
      float s = 0.f;
      for (int w = 0; w < NW; ++w) s += wpart[w][0][4 + tid];
      astore(&partials[PPART(0, g, c, 0) + 4 + tid], s);
    }
    gbar(fl, c, 1, tid, lane);
    if (tid < 128) {
      float s = 0.f;
#pragma unroll 8
      for (int cc = 0; cc < NB; ++cc) s += aload(&partials[PPART(0, g, cc, 0) + 4 + tid]);
      hmean[tid] = s * (1.0f / (float)Nn);
    }
    if (tid >= 128 && tid < 256) qprev[tid - 128] = dec_inp[tid - 128];
    __syncthreads();
    {  // base1[m][h] = sum_{i<128} hmean[i] * Wq1[m][i][h]
      const int o = tid & 255, part = tid >> 8;
      const int m = o >> 7, h = o & 127;
      const float* wp = Wq1 + (size_t)m * 256 * 128 + (size_t)(part * 32) * 128 + h;
      const float* qc = hmean + part * 32;
      float acc = 0.f;
#pragma unroll 16
      for (int i = 0; i < 32; ++i) acc += qc[i] * wp[(size_t)i * 128];
      qpart[part][o] = acc;
    }
    __syncthreads();
    if (tid < 256)
      base1[tid] = qpart[0][tid] + qpart[1][tid] + qpart[2][tid] + qpart[3][tid];
    __syncthreads();
  }

  int p = 2;  // next barrier phase id (monotonic)
  for (int step = 0; step < Ss; ++step) {
    for (int gl = 0; gl < 3; ++gl) {
      const float* r0p = pb + (size_t)(4 * gl + 0) * TPT;
      const float* r1p = pb + (size_t)(4 * gl + 1) * TPT;
      const float* v0p = pb + (size_t)(4 * gl + 2) * TPT;
      const float* v1p = pb + (size_t)(4 * gl + 3) * TPT;
      // HOISTED nontemporal streaming loads, pinned above the gemm (anti-sink)
      const f32x4 r0A = NTL(r0p + o1), r0B = NTL(r0p + o2);
      const f32x4 r1A = NTL(r1p + o1), r1B = NTL(r1p + o2);
      const f32x4 v0A = NTL(v0p + o1), v0B = NTL(v0p + o2);
      const f32x4 v1A = NTL(v1p + o1), v1B = NTL(v1p + o2);
      __builtin_amdgcn_sched_barrier(0);
      {  // q-proj: gl==0 -> base1 + qprev@Wq1_bot; else qcur@Wq (4-way split)
        const int o = tid & 255, part = tid >> 8;
        const int m = o >> 7, h = o & 127;
        const float* wp;
        const float* qc;
        if (gl == 0) {
          wp = Wq1 + (size_t)m * 256 * 128 + (size_t)(128 + part * 32) * 128 + h;
          qc = qprev + part * 32;
        } else {
          const float* Wq = (gl == 1) ? Wq3 : Wq4;
          wp = Wq + (size_t)m * 128 * 128 + (size_t)(part * 32) * 128 + h;
          qc = qcur + part * 32;
        }
        float acc = 0.f;
#pragma unroll 16
        for (int i = 0; i < 32; ++i) acc += qc[i] * wp[(size_t)i * 128];
        qpart[part][o] = acc;
      }
      __syncthreads();
      if (tid < 256) {
        float s = qpart[0][tid] + qpart[1][tid] + qpart[2][tid] + qpart[3][tid];
        if (gl == 0) s += base1[tid];
        (&qm[0][0])[tid] = s;
      }
      __syncthreads();

      const f32x4 qa = *(const f32x4*)&qm[0][h0];
      const f32x4 qb = *(const f32x4*)&qm[1][h0];
      const float mlA = maskl[jrow], mlB = maskl[j2c];
      float s0A = dot4t(qa, r0A, v0A), s1A = dot4t(qb, r1A, v1A);
      float s0B = dot4t(qa, r0B, v0B), s1B = dot4t(qb, r1B, v1B);
      red5_4(s0A, s1A, s0B, s1B);
      s0A = 10.f * tanh_fast(s0A) - 1e8f * mlA;
      s1A = 10.f * tanh_fast(s1A) - 1e8f * mlA;
      s0B = 10.f * tanh_fast(s0B) - 1e8f * mlB;
      s1B = 10.f * tanh_fast(s1B) - 1e8f * mlB;
      const float e0A = __expf(s0A - 10.f), e1A = __expf(s1A - 10.f);
      const float e0B = a2 ? __expf(s0B - 10.f) : 0.f;
      const float e1B = a2 ? __expf(s1B - 10.f) : 0.f;
      float S0 = e0A + e0B, S1 = e1A + e1B;
      f32x4 g0 = r0A * e0A + r0B * e0B;
      f32x4 g1 = r1A * e1A + r1B * e1B;
      S0 += __shfl_xor(S0, 32, 64); S1 += __shfl_xor(S1, 32, 64);
      g0[0] += __shfl_xor(g0[0], 32, 64); g0[1] += __shfl_xor(g0[1], 32, 64);
      g0[2] += __shfl_xor(g0[2], 32, 64); g0[3] += __shfl_xor(g0[3], 32, 64);
      g1[0] += __shfl_xor(g1[0], 32, 64); g1[1] += __shfl_xor(g1[1], 32, 64);
      g1[2] += __shfl_xor(g1[2], 32, 64); g1[3] += __shfl_xor(g1[3], 32, 64);
      if (half == 0) {
        *(f32x4*)&wpart[wv][0][4 + h0] = g0;
        *(f32x4*)&wpart[wv][1][4 + h0] = g1;
        if (hl == 0) { wpart[wv][0][0] = S0; wpart[wv][1][0] = S1; }
      }
      __syncthreads();
      float* ab = accum + ABUF(p & 3, g);
      float* zb = accum + ABUF((p + 1) & 3, g);
      if (tid < 256) {  // block combine -> atomic accumulate at coherence pt
        const int m = tid >> 7, h = tid & 127;
        float gs = 0.f;
        for (int w = 0; w < NW; ++w) gs += wpart[w][m][4 + h];
        unsafeAtomicAdd(&ab[m * 132 + 4 + h], gs);
        if (h == 0) {
          float ss = 0.f;
          for (int w = 0; w < NW; ++w) ss += wpart[w][m][0];
          unsafeAtomicAdd(&ab[m * 132], ss);
        }
      } else if (tid >= 512 && tid < 512 + 17) {  // zero next phase's buffer
        const int idx = c * 17 + (tid - 512);
        if (idx < 272) astore(&zb[idx], 0.f);
      }
      gbar(fl, c, p, tid, lane);
      p++;
      // group read: ONE coherent load per thread (sum already formed)
      if (tid < 256) gfraw[tid] = aload(&ab[(tid >> 7) * 132 + 4 + (tid & 127)]);
      if (tid >= 256 && tid < 258) sS[tid - 256] = aload(&ab[(tid - 256) * 132]);
      __syncthreads();
      {  // merge heads from LDS Wmh, divide folded in: q = (gx @ Wmh)/S
        const int h = tid & 127, part = tid >> 7;
        const int m = part >> 2;
        float acc = 0.f;
        const float* wl = Wmh_lds + (size_t)part * 32 * 128 + h;
        const float* gg = gfraw + part * 32;
#pragma unroll 16
        for (int i = 0; i < 32; ++i) acc += gg[i] * wl[i * 128];
        mpart[part][h] = acc / sS[m];
      }
      __syncthreads();
      if (tid < 128) {
        float acc = 0.f;
        for (int w = 0; w < 8; ++w) acc += mpart[w][tid];
        qcur[tid] = acc;
      }
      __syncthreads();
    }

    // ---- pointer ----
    const float* r2p = pb + (size_t)12 * TPT;
    const f32x4 rrA = NTL(r2p + o1);   // hoisted + pinned
    const f32x4 rrB = NTL(r2p + o2);
    __builtin_amdgcn_sched_barrier(0);
    {  // qptr = qcur @ Wq2 — 8-way split, seg 16
      const int h = tid & 127, part = tid >> 7;
      float acc = 0.f;
      const float* wp = Wq2 + (size_t)part * 16 * 128 + h;
      const float* qc = qcur + part * 16;
#pragma unroll
      for (int i = 0; i < 16; ++i) acc += qc[i] * wp[(size_t)i * 128];
      mpart[part][h] = acc;
    }
    __syncthreads();
    if (tid < 128) {
      float acc = 0.f;
      for (int w = 0; w < 8; ++w) acc += mpart[w][tid];
      qm[0][tid] = acc;
    }
    __syncthreads();
    {
      const f32x4 q2 = *(const f32x4*)&qm[0][h0];
      const f32x4 vz = *(const f32x4*)&vecl[h0];
      float upA = dot4t(q2, rrA, vz);
      float upB = dot4t(q2, rrB, vz);
      red5_2(upA, upB);
      const float mlA = maskl[jrow], mlB = maskl[j2c];
      const float uA = 10.f * tanh_fast(upA) - 1e8f * mlA;
      const float uB = a2 ? (10.f * tanh_fast(upB) - 1e8f * mlB) : -3.0e38f;
      if (hl == 0) {
        ulocal[jrow] = uA;
        if (a2) ulocal[j2] = uB;
      }
      float Sv = __expf(uA - 10.f) + (a2 ? __expf(uB - 10.f) : 0.f);
      float um = uA; int ui = start + jrow;
      if (a2 && uB > um) { um = uB; ui = start + j2; }
      Sv += __shfl_xor(Sv, 32, 64);
      const float um2 = __shfl_xor(um, 32, 64);
      const int ui2 = __shfl_xor(ui, 32, 64);
      if (um2 > um || (um2 == um && ui2 < ui)) { um = um2; ui = ui2; }
      if (lane == 0) {
        wpart[wv][0][0] = Sv; wpart[wv][0][1] = um;
        wpart[wv][0][2] = __int_as_float(ui);
      }
    }
    __syncthreads();
    float* ab = accum + ABUF(p & 3, g);
    float* zb = accum + ABUF((p + 1) & 3, g);
    if (tid == 0) {  // fused group argmax/logZ: 1 atomicAdd + 1 u64 atomicMax
      float St = 0.f, bm = -3.0e38f; int bi = 0x7fffffff;
      for (int ww = 0; ww < NW; ++ww) {
        St += wpart[ww][0][0];
        const float m2 = wpart[ww][0][1];
        const int i2 = __float_as_int(wpart[ww][0][2]);
        if (m2 > bm || (m2 == bm && i2 < bi)) { bm = m2; bi = i2; }
      }
      unsigned ob = __float_as_uint(bm);
      ob = (ob & 0x80000000u) ? ~ob : (ob | 0x80000000u);  // orderable float
      const unsigned long long key =
          ((unsigned long long)ob << 32) | (0xFFFFFFFFu - (unsigned)bi);
      unsafeAtomicAdd(&ab[0], St);
      atomicMax((unsigned long long*)&ab[264], key);
    } else if (tid >= 512 && tid < 512 + 17) {  // zero next phase's buffer
      const int idx = c * 17 + (tid - 512);
      if (idx < 272) astore(&zb[idx], 0.f);
    }
    gbar(fl, c, p, tid, lane);
    p++;
    if (tid == 0) {  // single coherent RT: St + packed key
      const float St = aload(&ab[0]);
      const unsigned long long key = __hip_atomic_load(
          (const unsigned long long*)&ab[264], __ATOMIC_RELAXED,
          __HIP_MEMORY_SCOPE_AGENT);
      sel_sh = (int)(0xFFFFFFFFu - (unsigned)(key & 0xFFFFFFFFu));
      logZ_sh = 10.f + __logf(St);
    }
    __syncthreads();
    const int sel = sel_sh;
    const float lz = logZ_sh;
    if (tid < 128)  // prefetch selected row for next step's glimpse-1
      qprev[tid] = enc[((size_t)g * Nn + sel) * Hh + tid];
    for (int j = tid; j < cnt; j += TPB)
      out[(size_t)step * (Bb * Nn) + (size_t)g * Nn + start + j] = ulocal[j] - lz;
    if (c == 0 && tid == 0)
      out[(size_t)Ss * Bb * Nn + (size_t)step * Bb + g] = (float)sel;
    if (tid == 0 && sel >= start && sel < start + cnt) maskl[sel - start] = 1.0f;
    __syncthreads();
  }
}

// -------------------------------------------------------------------- launch
extern "C" void kernel_launch(void* const* d_in, const int* in_sizes, int n_in,
                              void* d_out, int out_size, void* d_ws, size_t ws_size,
                              hipStream_t stream) {
  const float* enc     = (const float*)d_in[0];
  const float* mask0   = (const float*)d_in[1];
  const float* Wq1     = (const float*)d_in[2];
  const float* Wref1   = (const float*)d_in[3];
  const float* Vec1    = (const float*)d_in[4];
  const float* Wq3     = (const float*)d_in[5];
  const float* Wref3   = (const float*)d_in[6];
  const float* Vec3    = (const float*)d_in[7];
  const float* Wq4     = (const float*)d_in[8];
  const float* Wref4   = (const float*)d_in[9];
  const float* Vec4    = (const float*)d_in[10];
  const float* Wmh     = (const float*)d_in[11];
  const float* Wq2     = (const float*)d_in[12];
  const float* Wref2   = (const float*)d_in[13];
  const float* Vec2    = (const float*)d_in[14];
  const float* dec_inp = (const float*)d_in[15];
  float* out = (float*)d_out;

  char* ws = (char*)d_ws;
  int* flags      = (int*)ws;                          // 32,768 B
  float* accum    = (float*)(ws + 32768);              // 4*16*272*4 = 69,632 B
  float* partials = (float*)(ws + 102400);             // 540,672 B
  float* proj     = (float*)(ws + 102400 + 540672);    // 13 * 2,048,000 f32

  hipMemsetAsync(ws, 0, 102400, stream);  // zero flags + accum buffers

  dim3 pg(250, 26);
  ptr1_proj_kernel<<<pg, 256, 0, stream>>>(enc, Wref1, Vec1, Wref3, Vec3,
                                           Wref4, Vec4, Wref2, proj);

  void* args[] = {(void*)&enc,  (void*)&mask0, (void*)&Wq1, (void*)&Wq3,
                  (void*)&Wq4,  (void*)&Wmh,   (void*)&Wq2, (void*)&Vec2,
                  (void*)&dec_inp, (void*)&proj, (void*)&partials,
                  (void*)&accum, (void*)&flags, (void*)&out};
  hipLaunchCooperativeKernel((const void*)ptr1_decode_kernel, dim3(256),
                             dim3(1024), args, 0, stream);
}